// Round 1
// 473.460 us; speedup vs baseline: 1.3540x; 1.3540x over previous
//
#include <hip/hip_runtime.h>

#define HIDDEN 128
#define SCAN_B 1024

// ================= CSR build (per call; no fp atomics anywhere) =============
__global__ __launch_bounds__(256)
void k_hist(const int* __restrict__ dst, int* __restrict__ cnt, int E) {
    int e = blockIdx.x * 256 + threadIdx.x;
    if (e < E) atomicAdd(&cnt[dst[e]], 1);
}

// block-level inclusive scan -> exclusive offsets + block sums
__global__ __launch_bounds__(SCAN_B)
void k_scan1(const int* __restrict__ cnt, int* __restrict__ offs,
             int* __restrict__ bsum, int N) {
    __shared__ int sm[SCAN_B];
    int g = blockIdx.x * SCAN_B + threadIdx.x;
    int v = (g < N) ? cnt[g] : 0;
    int acc = v;
    sm[threadIdx.x] = v;
    __syncthreads();
    for (int d = 1; d < SCAN_B; d <<= 1) {
        int t = (threadIdx.x >= d) ? sm[threadIdx.x - d] : 0;
        __syncthreads();
        acc += t;
        sm[threadIdx.x] = acc;
        __syncthreads();
    }
    if (g < N) offs[g] = acc - v;                 // exclusive
    if (threadIdx.x == SCAN_B - 1) bsum[blockIdx.x] = acc;
}

__global__ __launch_bounds__(SCAN_B)
void k_scan2(int* __restrict__ bsum, int nb) {
    __shared__ int sm[SCAN_B];
    int v = (threadIdx.x < nb) ? bsum[threadIdx.x] : 0;
    int acc = v;
    sm[threadIdx.x] = v;
    __syncthreads();
    for (int d = 1; d < SCAN_B; d <<= 1) {
        int t = (threadIdx.x >= d) ? sm[threadIdx.x - d] : 0;
        __syncthreads();
        acc += t;
        sm[threadIdx.x] = acc;
        __syncthreads();
    }
    if (threadIdx.x < nb) bsum[threadIdx.x] = acc - v;   // exclusive
}

__global__ __launch_bounds__(SCAN_B)
void k_scan3(int* __restrict__ offs, const int* __restrict__ bsum, int N) {
    int g = blockIdx.x * SCAN_B + threadIdx.x;
    if (g < N) offs[g] += bsum[blockIdx.x];
}

__global__ __launch_bounds__(256)
void k_fill(const int* __restrict__ src, const int* __restrict__ dst,
            const float* __restrict__ ew, const int* __restrict__ offs,
            int* __restrict__ cursor, int* __restrict__ csrc,
            float* __restrict__ cw, int E) {
    int e = blockIdx.x * 256 + threadIdx.x;
    if (e >= E) return;
    int d = dst[e];
    int slot = offs[d] + atomicAdd(&cursor[d], 1);
    csrc[slot] = src[e];
    cw[slot]   = ew[e];
}

// ================= layer 1: gather 2ch + node update ========================
__global__ __launch_bounds__(256)
void k_gather2(const int* __restrict__ offs, const int* __restrict__ cnt,
               const int* __restrict__ csrc, const float* __restrict__ cw,
               const float* __restrict__ x, float* __restrict__ aggr, int N) {
    int i = blockIdx.x * 256 + threadIdx.x;
    if (i >= N) return;
    int start = offs[i], deg = cnt[i];
    float a0 = 0.f, a1 = 0.f;
    for (int j = 0; j < deg; ++j) {
        int   s = csrc[start + j];
        float w = cw[start + j];
        float2 xv = *reinterpret_cast<const float2*>(x + (size_t)s * 2);
        a0 = fmaf(w, xv.x, a0);
        a1 = fmaf(w, xv.y, a1);
    }
    aggr[(size_t)i * 2 + 0] = a0;
    aggr[(size_t)i * 2 + 1] = a1;
}

__global__ __launch_bounds__(256)
void k_node1(const float* __restrict__ aggr, const float* __restrict__ x,
             const float* __restrict__ Wrel, const float* __restrict__ b,
             const float* __restrict__ Wroot, float* __restrict__ h, int N) {
    int t = blockIdx.x * 256 + threadIdx.x;
    if (t >= N * HIDDEN) return;
    int c = t & (HIDDEN - 1);
    int i = t >> 7;
    float2 a  = *reinterpret_cast<const float2*>(aggr + (size_t)i * 2);
    float2 xv = *reinterpret_cast<const float2*>(x    + (size_t)i * 2);
    float v = b[c] + a.x * Wrel[c] + a.y * Wrel[HIDDEN + c]
                   + xv.x * Wroot[c] + xv.y * Wroot[HIDDEN + c];
    h[t] = fmaxf(v, 0.0f);
}

// ================= layer 2: wave-per-node 128ch gather ======================
__global__ __launch_bounds__(256)
void k_gather128(const int* __restrict__ offs, const int* __restrict__ cnt,
                 const int* __restrict__ csrc, const float* __restrict__ cw,
                 const float* __restrict__ h, float* __restrict__ aggr, int N) {
    int wv   = (blockIdx.x * 256 + threadIdx.x) >> 6;
    int lane = threadIdx.x & 63;
    if (wv >= N) return;
    int start = offs[wv], deg = cnt[wv];
    float2 acc = {0.f, 0.f};
    for (int base = 0; base < deg; base += 64) {
        int nb = min(64, deg - base);
        int   s = 0; float we = 0.f;
        if (lane < nb) {
            s  = csrc[start + base + lane];
            we = cw  [start + base + lane];
        }
        for (int k = 0; k < nb; ++k) {
            int   ss = __shfl(s,  k);
            float ww = __shfl(we, k);
            float2 v = *reinterpret_cast<const float2*>(h + (size_t)ss * HIDDEN + lane * 2);
            acc.x = fmaf(ww, v.x, acc.x);
            acc.y = fmaf(ww, v.y, acc.y);
        }
    }
    *reinterpret_cast<float2*>(aggr + (size_t)wv * HIDDEN + lane * 2) = acc;
}

// ================= layer 2 node update: LDS-tiled fp32 GEMM =================
// h2 = relu([aggr | h] @ [W2rel ; W2root] + b2), written IN PLACE over h.
// BM=64 nodes x BN=128 (all channels) per block, BK=64, 256 threads.
// Each thread: 4 nodes x 8 channels (two float4 groups at ci*4 and 64+ci*4).
#define BM2 64
#define XS_STRIDE 68   // 64 + 4 pad: keeps float4 alignment (272B rows) + bank spread

__global__ __launch_bounds__(256)
void k_node2(const float* __restrict__ aggr, float* __restrict__ h,
             const float* __restrict__ Wrel, const float* __restrict__ b,
             const float* __restrict__ Wroot, int N) {
    __shared__ float Xs[BM2 * XS_STRIDE];     // 64 x 64 input tile (+pad)
    __shared__ float Ws[64 * HIDDEN];         // 64 x 128 weight tile

    const int tid = threadIdx.x;
    const int ci  = tid & 15;                 // channel group: cols ci*4, 64+ci*4
    const int ri  = tid >> 4;                 // node group: rows ri*4 .. ri*4+3
    const int nb  = blockIdx.x * BM2;

    float acc[4][8];
    {
        float4 b0 = *reinterpret_cast<const float4*>(b + ci * 4);
        float4 b1 = *reinterpret_cast<const float4*>(b + 64 + ci * 4);
#pragma unroll
        for (int m = 0; m < 4; ++m) {
            acc[m][0] = b0.x; acc[m][1] = b0.y; acc[m][2] = b0.z; acc[m][3] = b0.w;
            acc[m][4] = b1.x; acc[m][5] = b1.y; acc[m][6] = b1.z; acc[m][7] = b1.w;
        }
    }

    // K = 256 total: tiles 0,1 = aggr @ Wrel (k 0..127), tiles 2,3 = h @ Wroot.
    for (int t = 0; t < 4; ++t) {
        const float* Xsrc = (t < 2) ? aggr : (const float*)h;
        const float* Wsrc = (t < 2) ? Wrel : Wroot;
        const int kc = (t & 1) * 64;          // column / weight-row offset

        __syncthreads();                      // previous compute done before overwrite
        // stage X tile: 64 rows x 64 cols, 4 float4 per thread (coalesced 256B/row)
#pragma unroll
        for (int q = 0; q < 4; ++q) {
            int idx = q * 256 + tid;          // 0..1023
            int row = idx >> 4;
            int c4  = (idx & 15) * 4;
            int gr  = nb + row; if (gr >= N) gr = N - 1;
            float4 v = *reinterpret_cast<const float4*>(Xsrc + (size_t)gr * HIDDEN + kc + c4);
            *reinterpret_cast<float4*>(&Xs[row * XS_STRIDE + c4]) = v;
        }
        // stage W tile: rows kc..kc+63 of [128][128], 8 float4 per thread
#pragma unroll
        for (int q = 0; q < 8; ++q) {
            int idx = q * 256 + tid;          // 0..2047
            int row = idx >> 5;
            int c4  = (idx & 31) * 4;
            float4 v = *reinterpret_cast<const float4*>(Wsrc + (size_t)(kc + row) * HIDDEN + c4);
            *reinterpret_cast<float4*>(&Ws[row * HIDDEN + c4]) = v;
        }
        __syncthreads();

        // compute: 64 k-steps, unrolled by 4 with float4 LDS reads
#pragma unroll
        for (int kk = 0; kk < 64; kk += 4) {
            float4 xr[4];
#pragma unroll
            for (int m = 0; m < 4; ++m)
                xr[m] = *reinterpret_cast<const float4*>(&Xs[(ri * 4 + m) * XS_STRIDE + kk]);
#pragma unroll
            for (int j = 0; j < 4; ++j) {
                float4 w0 = *reinterpret_cast<const float4*>(&Ws[(kk + j) * HIDDEN + ci * 4]);
                float4 w1 = *reinterpret_cast<const float4*>(&Ws[(kk + j) * HIDDEN + 64 + ci * 4]);
#pragma unroll
                for (int m = 0; m < 4; ++m) {
                    float xm = (j == 0) ? xr[m].x : (j == 1) ? xr[m].y
                             : (j == 2) ? xr[m].z : xr[m].w;
                    acc[m][0] = fmaf(xm, w0.x, acc[m][0]);
                    acc[m][1] = fmaf(xm, w0.y, acc[m][1]);
                    acc[m][2] = fmaf(xm, w0.z, acc[m][2]);
                    acc[m][3] = fmaf(xm, w0.w, acc[m][3]);
                    acc[m][4] = fmaf(xm, w1.x, acc[m][4]);
                    acc[m][5] = fmaf(xm, w1.y, acc[m][5]);
                    acc[m][6] = fmaf(xm, w1.z, acc[m][6]);
                    acc[m][7] = fmaf(xm, w1.w, acc[m][7]);
                }
            }
        }
    }

    // relu + in-place store (all global reads of h completed before last barrier)
#pragma unroll
    for (int m = 0; m < 4; ++m) {
        int node = nb + ri * 4 + m;
        if (node < N) {
            float4 o0, o1;
            o0.x = fmaxf(acc[m][0], 0.f); o0.y = fmaxf(acc[m][1], 0.f);
            o0.z = fmaxf(acc[m][2], 0.f); o0.w = fmaxf(acc[m][3], 0.f);
            o1.x = fmaxf(acc[m][4], 0.f); o1.y = fmaxf(acc[m][5], 0.f);
            o1.z = fmaxf(acc[m][6], 0.f); o1.w = fmaxf(acc[m][7], 0.f);
            float* o = h + (size_t)node * HIDDEN;
            *reinterpret_cast<float4*>(o + ci * 4)      = o0;
            *reinterpret_cast<float4*>(o + 64 + ci * 4) = o1;
        }
    }
}

// ================= layer 3: project to 3ch, then gather =====================
__global__ __launch_bounds__(256)
void k_node3(const float* __restrict__ h2,
             const float* __restrict__ Wrel, const float* __restrict__ b,
             const float* __restrict__ Wroot,
             float* __restrict__ z, float* __restrict__ out, int N) {
    int i = blockIdx.x * 256 + threadIdx.x;
    if (i >= N) return;
    float zr[3] = {0.f, 0.f, 0.f};
    float zo[3] = {b[0], b[1], b[2]};
    const float4* h4 = reinterpret_cast<const float4*>(h2 + (size_t)i * HIDDEN);
    for (int kk = 0; kk < HIDDEN / 4; ++kk) {
        float4 hv = h4[kk];
#pragma unroll
        for (int j = 0; j < 4; ++j) {
            int k = kk * 4 + j;
            float hj = (j == 0) ? hv.x : (j == 1) ? hv.y : (j == 2) ? hv.z : hv.w;
#pragma unroll
            for (int c = 0; c < 3; ++c) {
                zr[c] = fmaf(hj, Wrel [k * 3 + c], zr[c]);
                zo[c] = fmaf(hj, Wroot[k * 3 + c], zo[c]);
            }
        }
    }
    z[(size_t)i * 3 + 0] = zr[0]; z[(size_t)i * 3 + 1] = zr[1]; z[(size_t)i * 3 + 2] = zr[2];
    out[(size_t)i * 3 + 0] = zo[0]; out[(size_t)i * 3 + 1] = zo[1]; out[(size_t)i * 3 + 2] = zo[2];
}

__global__ __launch_bounds__(256)
void k_gather3(const int* __restrict__ offs, const int* __restrict__ cnt,
               const int* __restrict__ csrc, const float* __restrict__ cw,
               const float* __restrict__ z, float* __restrict__ out, int N) {
    int i = blockIdx.x * 256 + threadIdx.x;
    if (i >= N) return;
    int start = offs[i], deg = cnt[i];
    float a0 = 0.f, a1 = 0.f, a2 = 0.f;
    for (int j = 0; j < deg; ++j) {
        int   s = csrc[start + j];
        float w = cw[start + j];
        const float* zp = z + (size_t)s * 3;
        a0 = fmaf(w, zp[0], a0);
        a1 = fmaf(w, zp[1], a1);
        a2 = fmaf(w, zp[2], a2);
    }
    out[(size_t)i * 3 + 0] += a0;
    out[(size_t)i * 3 + 1] += a1;
    out[(size_t)i * 3 + 2] += a2;
}

extern "C" void kernel_launch(void* const* d_in, const int* in_sizes, int n_in,
                              void* d_out, int out_size, void* d_ws, size_t ws_size,
                              hipStream_t stream) {
    const float* x      = (const float*)d_in[0];
    const int*   ei     = (const int*)  d_in[1];
    const float* ew     = (const float*)d_in[2];
    const float* W1rel  = (const float*)d_in[4];
    const float* b1     = (const float*)d_in[5];
    const float* W1root = (const float*)d_in[6];
    const float* W2rel  = (const float*)d_in[7];
    const float* b2     = (const float*)d_in[8];
    const float* W2root = (const float*)d_in[9];
    const float* W3rel  = (const float*)d_in[10];
    const float* b3     = (const float*)d_in[11];
    const float* W3root = (const float*)d_in[12];
    float* out = (float*)d_out;

    const int N = in_sizes[0] / 2;
    const int E = in_sizes[2];
    const int* src = ei;
    const int* dst = ei + E;

    // -------- workspace layout --------
    // h    : N*128 f32  (h1, overwritten in place by h2)
    // aggr : N*128 f32  (layer-2 aggregation; front reused for aggr1[N*2] and z[N*3])
    // offs : N int | cnt : N int | cursor : N int | bsum : SCAN_B int
    // csrc : E int | cw : E f32
    float* h    = (float*)d_ws;
    float* aggr = h + (size_t)N * HIDDEN;
    int*   offs   = (int*)(aggr + (size_t)N * HIDDEN);
    int*   cnt    = offs + N;
    int*   cursor = cnt + N;
    int*   bsum   = cursor + N;
    int*   csrc   = bsum + SCAN_B;
    float* cw     = (float*)(csrc + E);

    const int nbScan = (N + SCAN_B - 1) / SCAN_B;

    // -------- CSR build --------
    hipMemsetAsync(cnt, 0, (size_t)N * sizeof(int), stream);
    hipMemsetAsync(cursor, 0, (size_t)N * sizeof(int), stream);
    k_hist <<<(E + 255) / 256, 256, 0, stream>>>(dst, cnt, E);
    k_scan1<<<nbScan, SCAN_B, 0, stream>>>(cnt, offs, bsum, N);
    k_scan2<<<1, SCAN_B, 0, stream>>>(bsum, nbScan);
    k_scan3<<<nbScan, SCAN_B, 0, stream>>>(offs, bsum, N);
    k_fill <<<(E + 255) / 256, 256, 0, stream>>>(src, dst, ew, offs, cursor, csrc, cw, E);

    // -------- layer 1 --------
    k_gather2<<<(N + 255) / 256, 256, 0, stream>>>(offs, cnt, csrc, cw, x, aggr, N);
    k_node1  <<<(N * HIDDEN + 255) / 256, 256, 0, stream>>>(aggr, x, W1rel, b1, W1root, h, N);

    // -------- layer 2 --------
    {
        long long threads = (long long)N * 64;
        k_gather128<<<(int)((threads + 255) / 256), 256, 0, stream>>>(offs, cnt, csrc, cw, h, aggr, N);
    }
    k_node2<<<(N + BM2 - 1) / BM2, 256, 0, stream>>>(aggr, h, W2rel, b2, W2root, N);

    // -------- layer 3 --------
    float* z = aggr;   // aggr dead after node2; reuse front N*3 for z
    k_node3  <<<(N + 255) / 256, 256, 0, stream>>>(h, W3rel, b3, W3root, z, out, N);
    k_gather3<<<(N + 255) / 256, 256, 0, stream>>>(offs, cnt, csrc, cw, z, out, N);
}

// Round 2
// 396.504 us; speedup vs baseline: 1.6168x; 1.1941x over previous
//
#include <hip/hip_runtime.h>

#define HIDDEN 128
#define SCAN_B 1024

// ================= CSR build (per call; no fp atomics anywhere) =============
// k_hist also records each edge's rank within its dst bucket (atomic return),
// so k_fill needs no second atomic pass.
__global__ __launch_bounds__(256)
void k_hist(const int* __restrict__ dst, int* __restrict__ cnt,
            int* __restrict__ rank, int E) {
    int e = blockIdx.x * 256 + threadIdx.x;
    if (e < E) rank[e] = atomicAdd(&cnt[dst[e]], 1);
}

// block-level inclusive scan -> exclusive offsets + block sums
__global__ __launch_bounds__(SCAN_B)
void k_scan1(const int* __restrict__ cnt, int* __restrict__ offs,
             int* __restrict__ bsum, int N) {
    __shared__ int sm[SCAN_B];
    int g = blockIdx.x * SCAN_B + threadIdx.x;
    int v = (g < N) ? cnt[g] : 0;
    int acc = v;
    sm[threadIdx.x] = v;
    __syncthreads();
    for (int d = 1; d < SCAN_B; d <<= 1) {
        int t = (threadIdx.x >= d) ? sm[threadIdx.x - d] : 0;
        __syncthreads();
        acc += t;
        sm[threadIdx.x] = acc;
        __syncthreads();
    }
    if (g < N) offs[g] = acc - v;                 // exclusive
    if (threadIdx.x == SCAN_B - 1) bsum[blockIdx.x] = acc;
}

__global__ __launch_bounds__(SCAN_B)
void k_scan2(int* __restrict__ bsum, int nb) {
    __shared__ int sm[SCAN_B];
    int v = (threadIdx.x < nb) ? bsum[threadIdx.x] : 0;
    int acc = v;
    sm[threadIdx.x] = v;
    __syncthreads();
    for (int d = 1; d < SCAN_B; d <<= 1) {
        int t = (threadIdx.x >= d) ? sm[threadIdx.x - d] : 0;
        __syncthreads();
        acc += t;
        sm[threadIdx.x] = acc;
        __syncthreads();
    }
    if (threadIdx.x < nb) bsum[threadIdx.x] = acc - v;   // exclusive
}

__global__ __launch_bounds__(SCAN_B)
void k_scan3(int* __restrict__ offs, const int* __restrict__ bsum, int N) {
    int g = blockIdx.x * SCAN_B + threadIdx.x;
    if (g < N) offs[g] += bsum[blockIdx.x];
}

// Scatter edges into CSR order. One 8B packed store per edge (src, w) —
// halves scattered-line traffic vs two 4B stores; no atomics (rank precomputed).
__global__ __launch_bounds__(256)
void k_fill(const int* __restrict__ src, const int* __restrict__ dst,
            const float* __restrict__ ew, const int* __restrict__ offs,
            const int* __restrict__ rank, int2* __restrict__ cpack, int E) {
    int e = blockIdx.x * 256 + threadIdx.x;
    if (e >= E) return;
    int d = dst[e];
    int slot = offs[d] + rank[e];
    int2 p;
    p.x = src[e];
    p.y = __float_as_int(ew[e]);
    cpack[slot] = p;
}

// ================= layer 1: gather 2ch + node update ========================
__global__ __launch_bounds__(256)
void k_gather2(const int* __restrict__ offs, const int* __restrict__ cnt,
               const int2* __restrict__ cpack,
               const float* __restrict__ x, float* __restrict__ aggr, int N) {
    int i = blockIdx.x * 256 + threadIdx.x;
    if (i >= N) return;
    int start = offs[i], deg = cnt[i];
    float a0 = 0.f, a1 = 0.f;
    for (int j = 0; j < deg; ++j) {
        int2  p = cpack[start + j];
        int   s = p.x;
        float w = __int_as_float(p.y);
        float2 xv = *reinterpret_cast<const float2*>(x + (size_t)s * 2);
        a0 = fmaf(w, xv.x, a0);
        a1 = fmaf(w, xv.y, a1);
    }
    aggr[(size_t)i * 2 + 0] = a0;
    aggr[(size_t)i * 2 + 1] = a1;
}

__global__ __launch_bounds__(256)
void k_node1(const float* __restrict__ aggr, const float* __restrict__ x,
             const float* __restrict__ Wrel, const float* __restrict__ b,
             const float* __restrict__ Wroot, float* __restrict__ h, int N) {
    int t = blockIdx.x * 256 + threadIdx.x;
    if (t >= N * HIDDEN) return;
    int c = t & (HIDDEN - 1);
    int i = t >> 7;
    float2 a  = *reinterpret_cast<const float2*>(aggr + (size_t)i * 2);
    float2 xv = *reinterpret_cast<const float2*>(x    + (size_t)i * 2);
    float v = b[c] + a.x * Wrel[c] + a.y * Wrel[HIDDEN + c]
                   + xv.x * Wroot[c] + xv.y * Wroot[HIDDEN + c];
    h[t] = fmaxf(v, 0.0f);
}

// ================= layer 2: wave-per-node 128ch gather ======================
__global__ __launch_bounds__(256)
void k_gather128(const int* __restrict__ offs, const int* __restrict__ cnt,
                 const int2* __restrict__ cpack,
                 const float* __restrict__ h, float* __restrict__ aggr, int N) {
    int wv   = (blockIdx.x * 256 + threadIdx.x) >> 6;
    int lane = threadIdx.x & 63;
    if (wv >= N) return;
    int start = offs[wv], deg = cnt[wv];
    float2 acc = {0.f, 0.f};
    for (int base = 0; base < deg; base += 64) {
        int nb = min(64, deg - base);
        int   s = 0; float we = 0.f;
        if (lane < nb) {
            int2 p = cpack[start + base + lane];
            s  = p.x;
            we = __int_as_float(p.y);
        }
        for (int k = 0; k < nb; ++k) {
            int   ss = __shfl(s,  k);
            float ww = __shfl(we, k);
            float2 v = *reinterpret_cast<const float2*>(h + (size_t)ss * HIDDEN + lane * 2);
            acc.x = fmaf(ww, v.x, acc.x);
            acc.y = fmaf(ww, v.y, acc.y);
        }
    }
    *reinterpret_cast<float2*>(aggr + (size_t)wv * HIDDEN + lane * 2) = acc;
}

// ================= layer 2 node update: LDS-tiled fp32 GEMM =================
// h2 = relu([aggr | h] @ [W2rel ; W2root] + b2), written IN PLACE over h.
// BM=64 nodes x BN=128 (all channels) per block, BK=64, 256 threads.
// Each thread: 4 nodes x 8 channels (two float4 groups at ci*4 and 64+ci*4).
#define BM2 64
#define XS_STRIDE 68   // 64 + 4 pad: keeps float4 alignment (272B rows) + bank spread

__global__ __launch_bounds__(256)
void k_node2(const float* __restrict__ aggr, float* __restrict__ h,
             const float* __restrict__ Wrel, const float* __restrict__ b,
             const float* __restrict__ Wroot, int N) {
    __shared__ float Xs[BM2 * XS_STRIDE];     // 64 x 64 input tile (+pad)
    __shared__ float Ws[64 * HIDDEN];         // 64 x 128 weight tile

    const int tid = threadIdx.x;
    const int ci  = tid & 15;                 // channel group: cols ci*4, 64+ci*4
    const int ri  = tid >> 4;                 // node group: rows ri*4 .. ri*4+3
    const int nb  = blockIdx.x * BM2;

    float acc[4][8];
    {
        float4 b0 = *reinterpret_cast<const float4*>(b + ci * 4);
        float4 b1 = *reinterpret_cast<const float4*>(b + 64 + ci * 4);
#pragma unroll
        for (int m = 0; m < 4; ++m) {
            acc[m][0] = b0.x; acc[m][1] = b0.y; acc[m][2] = b0.z; acc[m][3] = b0.w;
            acc[m][4] = b1.x; acc[m][5] = b1.y; acc[m][6] = b1.z; acc[m][7] = b1.w;
        }
    }

    // K = 256 total: tiles 0,1 = aggr @ Wrel (k 0..127), tiles 2,3 = h @ Wroot.
    for (int t = 0; t < 4; ++t) {
        const float* Xsrc = (t < 2) ? aggr : (const float*)h;
        const float* Wsrc = (t < 2) ? Wrel : Wroot;
        const int kc = (t & 1) * 64;          // column / weight-row offset

        __syncthreads();                      // previous compute done before overwrite
        // stage X tile: 64 rows x 64 cols, 4 float4 per thread (coalesced 256B/row)
#pragma unroll
        for (int q = 0; q < 4; ++q) {
            int idx = q * 256 + tid;          // 0..1023
            int row = idx >> 4;
            int c4  = (idx & 15) * 4;
            int gr  = nb + row; if (gr >= N) gr = N - 1;
            float4 v = *reinterpret_cast<const float4*>(Xsrc + (size_t)gr * HIDDEN + kc + c4);
            *reinterpret_cast<float4*>(&Xs[row * XS_STRIDE + c4]) = v;
        }
        // stage W tile: rows kc..kc+63 of [128][128], 8 float4 per thread
#pragma unroll
        for (int q = 0; q < 8; ++q) {
            int idx = q * 256 + tid;          // 0..2047
            int row = idx >> 5;
            int c4  = (idx & 31) * 4;
            float4 v = *reinterpret_cast<const float4*>(Wsrc + (size_t)(kc + row) * HIDDEN + c4);
            *reinterpret_cast<float4*>(&Ws[row * HIDDEN + c4]) = v;
        }
        __syncthreads();

        // compute: 64 k-steps, unrolled by 4 with float4 LDS reads
#pragma unroll
        for (int kk = 0; kk < 64; kk += 4) {
            float4 xr[4];
#pragma unroll
            for (int m = 0; m < 4; ++m)
                xr[m] = *reinterpret_cast<const float4*>(&Xs[(ri * 4 + m) * XS_STRIDE + kk]);
#pragma unroll
            for (int j = 0; j < 4; ++j) {
                float4 w0 = *reinterpret_cast<const float4*>(&Ws[(kk + j) * HIDDEN + ci * 4]);
                float4 w1 = *reinterpret_cast<const float4*>(&Ws[(kk + j) * HIDDEN + 64 + ci * 4]);
#pragma unroll
                for (int m = 0; m < 4; ++m) {
                    float xm = (j == 0) ? xr[m].x : (j == 1) ? xr[m].y
                             : (j == 2) ? xr[m].z : xr[m].w;
                    acc[m][0] = fmaf(xm, w0.x, acc[m][0]);
                    acc[m][1] = fmaf(xm, w0.y, acc[m][1]);
                    acc[m][2] = fmaf(xm, w0.z, acc[m][2]);
                    acc[m][3] = fmaf(xm, w0.w, acc[m][3]);
                    acc[m][4] = fmaf(xm, w1.x, acc[m][4]);
                    acc[m][5] = fmaf(xm, w1.y, acc[m][5]);
                    acc[m][6] = fmaf(xm, w1.z, acc[m][6]);
                    acc[m][7] = fmaf(xm, w1.w, acc[m][7]);
                }
            }
        }
    }

    // relu + in-place store (all global reads of h completed before last barrier)
#pragma unroll
    for (int m = 0; m < 4; ++m) {
        int node = nb + ri * 4 + m;
        if (node < N) {
            float4 o0, o1;
            o0.x = fmaxf(acc[m][0], 0.f); o0.y = fmaxf(acc[m][1], 0.f);
            o0.z = fmaxf(acc[m][2], 0.f); o0.w = fmaxf(acc[m][3], 0.f);
            o1.x = fmaxf(acc[m][4], 0.f); o1.y = fmaxf(acc[m][5], 0.f);
            o1.z = fmaxf(acc[m][6], 0.f); o1.w = fmaxf(acc[m][7], 0.f);
            float* o = h + (size_t)node * HIDDEN;
            *reinterpret_cast<float4*>(o + ci * 4)      = o0;
            *reinterpret_cast<float4*>(o + 64 + ci * 4) = o1;
        }
    }
}

// ================= layer 3: project to 3ch, then gather =====================
__global__ __launch_bounds__(256)
void k_node3(const float* __restrict__ h2,
             const float* __restrict__ Wrel, const float* __restrict__ b,
             const float* __restrict__ Wroot,
             float* __restrict__ z, float* __restrict__ out, int N) {
    int i = blockIdx.x * 256 + threadIdx.x;
    if (i >= N) return;
    float zr[3] = {0.f, 0.f, 0.f};
    float zo[3] = {b[0], b[1], b[2]};
    const float4* h4 = reinterpret_cast<const float4*>(h2 + (size_t)i * HIDDEN);
    for (int kk = 0; kk < HIDDEN / 4; ++kk) {
        float4 hv = h4[kk];
#pragma unroll
        for (int j = 0; j < 4; ++j) {
            int k = kk * 4 + j;
            float hj = (j == 0) ? hv.x : (j == 1) ? hv.y : (j == 2) ? hv.z : hv.w;
#pragma unroll
            for (int c = 0; c < 3; ++c) {
                zr[c] = fmaf(hj, Wrel [k * 3 + c], zr[c]);
                zo[c] = fmaf(hj, Wroot[k * 3 + c], zo[c]);
            }
        }
    }
    z[(size_t)i * 3 + 0] = zr[0]; z[(size_t)i * 3 + 1] = zr[1]; z[(size_t)i * 3 + 2] = zr[2];
    out[(size_t)i * 3 + 0] = zo[0]; out[(size_t)i * 3 + 1] = zo[1]; out[(size_t)i * 3 + 2] = zo[2];
}

__global__ __launch_bounds__(256)
void k_gather3(const int* __restrict__ offs, const int* __restrict__ cnt,
               const int2* __restrict__ cpack,
               const float* __restrict__ z, float* __restrict__ out, int N) {
    int i = blockIdx.x * 256 + threadIdx.x;
    if (i >= N) return;
    int start = offs[i], deg = cnt[i];
    float a0 = 0.f, a1 = 0.f, a2 = 0.f;
    for (int j = 0; j < deg; ++j) {
        int2  p = cpack[start + j];
        int   s = p.x;
        float w = __int_as_float(p.y);
        const float* zp = z + (size_t)s * 3;
        a0 = fmaf(w, zp[0], a0);
        a1 = fmaf(w, zp[1], a1);
        a2 = fmaf(w, zp[2], a2);
    }
    out[(size_t)i * 3 + 0] += a0;
    out[(size_t)i * 3 + 1] += a1;
    out[(size_t)i * 3 + 2] += a2;
}

extern "C" void kernel_launch(void* const* d_in, const int* in_sizes, int n_in,
                              void* d_out, int out_size, void* d_ws, size_t ws_size,
                              hipStream_t stream) {
    const float* x      = (const float*)d_in[0];
    const int*   ei     = (const int*)  d_in[1];
    const float* ew     = (const float*)d_in[2];
    const float* W1rel  = (const float*)d_in[4];
    const float* b1     = (const float*)d_in[5];
    const float* W1root = (const float*)d_in[6];
    const float* W2rel  = (const float*)d_in[7];
    const float* b2     = (const float*)d_in[8];
    const float* W2root = (const float*)d_in[9];
    const float* W3rel  = (const float*)d_in[10];
    const float* b3     = (const float*)d_in[11];
    const float* W3root = (const float*)d_in[12];
    float* out = (float*)d_out;

    const int N = in_sizes[0] / 2;
    const int E = in_sizes[2];
    const int* src = ei;
    const int* dst = ei + E;

    // -------- workspace layout --------
    // h    : N*128 f32  (h1, overwritten in place by h2; front E ints alias rank
    //        during CSR build — rank dead before k_node1 writes h)
    // aggr : N*128 f32  (layer-2 aggregation; front reused for aggr1[N*2] and z[N*3])
    // offs : N int | cnt : N int | bsum : SCAN_B int
    // cpack: E int2 (src, weight-bits), 8B-aligned
    float* h    = (float*)d_ws;
    float* aggr = h + (size_t)N * HIDDEN;
    int*   offs = (int*)(aggr + (size_t)N * HIDDEN);
    int*   cnt  = offs + N;
    int*   bsum = cnt + N;
    int*   rank = (int*)h;                 // alias: used only hist->fill
    size_t cpo  = (size_t)(bsum + SCAN_B - (int*)d_ws);
    cpo = (cpo + 1) & ~(size_t)1;          // round up to 8B alignment
    int2*  cpack = (int2*)((int*)d_ws + cpo);

    const int nbScan = (N + SCAN_B - 1) / SCAN_B;

    // -------- CSR build --------
    hipMemsetAsync(cnt, 0, (size_t)N * sizeof(int), stream);
    k_hist <<<(E + 255) / 256, 256, 0, stream>>>(dst, cnt, rank, E);
    k_scan1<<<nbScan, SCAN_B, 0, stream>>>(cnt, offs, bsum, N);
    k_scan2<<<1, SCAN_B, 0, stream>>>(bsum, nbScan);
    k_scan3<<<nbScan, SCAN_B, 0, stream>>>(offs, bsum, N);
    k_fill <<<(E + 255) / 256, 256, 0, stream>>>(src, dst, ew, offs, rank, cpack, E);

    // -------- layer 1 --------
    k_gather2<<<(N + 255) / 256, 256, 0, stream>>>(offs, cnt, cpack, x, aggr, N);
    k_node1  <<<(N * HIDDEN + 255) / 256, 256, 0, stream>>>(aggr, x, W1rel, b1, W1root, h, N);

    // -------- layer 2 --------
    {
        long long threads = (long long)N * 64;
        k_gather128<<<(int)((threads + 255) / 256), 256, 0, stream>>>(offs, cnt, cpack, h, aggr, N);
    }
    k_node2<<<(N + BM2 - 1) / BM2, 256, 0, stream>>>(aggr, h, W2rel, b2, W2root, N);

    // -------- layer 3 --------
    float* z = aggr;   // aggr dead after node2; reuse front N*3 for z
    k_node3  <<<(N + 255) / 256, 256, 0, stream>>>(h, W3rel, b3, W3root, z, out, N);
    k_gather3<<<(N + 255) / 256, 256, 0, stream>>>(offs, cnt, cpack, z, out, N);
}

// Round 3
// 363.998 us; speedup vs baseline: 1.7612x; 1.0893x over previous
//
#include <hip/hip_runtime.h>

#define HIDDEN 128
#define SCAN_B 1024

// ================= CSR build (per call; no fp atomics anywhere) =============
// k_hist also records each edge's rank within its dst bucket (atomic return),
// so k_fill needs no second atomic pass.
__global__ __launch_bounds__(256)
void k_hist(const int* __restrict__ dst, int* __restrict__ cnt,
            int* __restrict__ rank, int E) {
    int e = blockIdx.x * 256 + threadIdx.x;
    if (e < E) rank[e] = atomicAdd(&cnt[dst[e]], 1);
}

// block-level inclusive scan -> exclusive offsets + block sums
__global__ __launch_bounds__(SCAN_B)
void k_scan1(const int* __restrict__ cnt, int* __restrict__ offs,
             int* __restrict__ bsum, int N) {
    __shared__ int sm[SCAN_B];
    int g = blockIdx.x * SCAN_B + threadIdx.x;
    int v = (g < N) ? cnt[g] : 0;
    int acc = v;
    sm[threadIdx.x] = v;
    __syncthreads();
    for (int d = 1; d < SCAN_B; d <<= 1) {
        int t = (threadIdx.x >= d) ? sm[threadIdx.x - d] : 0;
        __syncthreads();
        acc += t;
        sm[threadIdx.x] = acc;
        __syncthreads();
    }
    if (g < N) offs[g] = acc - v;                 // exclusive
    if (threadIdx.x == SCAN_B - 1) bsum[blockIdx.x] = acc;
}

__global__ __launch_bounds__(SCAN_B)
void k_scan2(int* __restrict__ bsum, int nb) {
    __shared__ int sm[SCAN_B];
    int v = (threadIdx.x < nb) ? bsum[threadIdx.x] : 0;
    int acc = v;
    sm[threadIdx.x] = v;
    __syncthreads();
    for (int d = 1; d < SCAN_B; d <<= 1) {
        int t = (threadIdx.x >= d) ? sm[threadIdx.x - d] : 0;
        __syncthreads();
        acc += t;
        sm[threadIdx.x] = acc;
        __syncthreads();
    }
    if (threadIdx.x < nb) bsum[threadIdx.x] = acc - v;   // exclusive
}

__global__ __launch_bounds__(SCAN_B)
void k_scan3(int* __restrict__ offs, const int* __restrict__ bsum, int N) {
    int g = blockIdx.x * SCAN_B + threadIdx.x;
    if (g < N) offs[g] += bsum[blockIdx.x];
}

// Scatter edges into CSR order. One 8B packed store per edge (src, w).
__global__ __launch_bounds__(256)
void k_fill(const int* __restrict__ src, const int* __restrict__ dst,
            const float* __restrict__ ew, const int* __restrict__ offs,
            const int* __restrict__ rank, int2* __restrict__ cpack, int E) {
    int e = blockIdx.x * 256 + threadIdx.x;
    if (e >= E) return;
    int d = dst[e];
    int slot = offs[d] + rank[e];
    int2 p;
    p.x = src[e];
    p.y = __float_as_int(ew[e]);
    cpack[slot] = p;
}

// degree from offs-diff (offs has N entries; last degree uses E)
__device__ __forceinline__ int deg_of(const int* offs, int i, int N, int E) {
    int s = offs[i];
    int e = (i + 1 < N) ? offs[i + 1] : E;
    return e - s;
}

// ================= layer 1: gather 2ch into aggr1 ===========================
__global__ __launch_bounds__(256)
void k_gather2(const int* __restrict__ offs, const int2* __restrict__ cpack,
               const float* __restrict__ x, float2* __restrict__ aggr1,
               int N, int E) {
    int i = blockIdx.x * 256 + threadIdx.x;
    if (i >= N) return;
    int start = offs[i], deg = deg_of(offs, i, N, E);
    float a0 = 0.f, a1 = 0.f;
    for (int j = 0; j < deg; ++j) {
        int2  p = cpack[start + j];
        int   s = p.x;
        float w = __int_as_float(p.y);
        float2 xv = *reinterpret_cast<const float2*>(x + (size_t)s * 2);
        a0 = fmaf(w, xv.x, a0);
        a1 = fmaf(w, xv.y, a1);
    }
    aggr1[i] = make_float2(a0, a1);
}

// ================= fused layer-2 aggregation + layer-1 node update ==========
// Per edge, instead of gathering the 512B materialized h1[src] row, RECOMPUTE
// it from 4 scalars (aggr1[src], x[src]) — both arrays are 800KB, L2-resident.
// Wave per dst node; lane l owns channels (2l, 2l+1); layer-1 weights for
// those channels live in registers. Epilogue also writes the wave's own h1
// row (k_node1 is fused away).
__global__ __launch_bounds__(256)
void k_gatherfused(const int* __restrict__ offs, const int2* __restrict__ cpack,
                   const float2* __restrict__ aggr1, const float* __restrict__ x,
                   const float* __restrict__ W1rel, const float* __restrict__ b1,
                   const float* __restrict__ W1root,
                   float* __restrict__ h, float* __restrict__ aggr,
                   int N, int E) {
    int wv   = (blockIdx.x * 256 + threadIdx.x) >> 6;
    int lane = threadIdx.x & 63;
    if (wv >= N) return;

    const int c0 = lane * 2;
    // layer-1 weights for this lane's 2 channels
    const float2 wr0 = *reinterpret_cast<const float2*>(W1rel  + c0);
    const float2 wr1 = *reinterpret_cast<const float2*>(W1rel  + HIDDEN + c0);
    const float2 wo0 = *reinterpret_cast<const float2*>(W1root + c0);
    const float2 wo1 = *reinterpret_cast<const float2*>(W1root + HIDDEN + c0);
    const float2 bb  = *reinterpret_cast<const float2*>(b1 + c0);

    int start = offs[wv], deg = deg_of(offs, wv, N, E);
    float2 acc = {0.f, 0.f};

    for (int base = 0; base < deg; base += 64) {
        int nb = min(64, deg - base);
        int sx = 0, wb = 0;
        if (lane < nb) {
            int2 p = cpack[start + base + lane];
            sx = p.x; wb = p.y;
        }
        int k = 0;
        // paired edges: two independent loads in flight per iteration
        for (; k + 1 < nb; k += 2) {
            int   s0 = __shfl(sx, k),     s1 = __shfl(sx, k + 1);
            float w0 = __int_as_float(__shfl(wb, k));
            float w1 = __int_as_float(__shfl(wb, k + 1));
            float2 a0 = aggr1[s0];
            float2 x0 = *reinterpret_cast<const float2*>(x + (size_t)s0 * 2);
            float2 a1 = aggr1[s1];
            float2 x1 = *reinterpret_cast<const float2*>(x + (size_t)s1 * 2);

            float p0 = fmaf(a0.x, wr0.x, bb.x); p0 = fmaf(a0.y, wr1.x, p0);
            p0 = fmaf(x0.x, wo0.x, p0);         p0 = fmaf(x0.y, wo1.x, p0);
            float q0 = fmaf(a0.x, wr0.y, bb.y); q0 = fmaf(a0.y, wr1.y, q0);
            q0 = fmaf(x0.x, wo0.y, q0);         q0 = fmaf(x0.y, wo1.y, q0);
            acc.x = fmaf(w0, fmaxf(p0, 0.f), acc.x);
            acc.y = fmaf(w0, fmaxf(q0, 0.f), acc.y);

            float p1 = fmaf(a1.x, wr0.x, bb.x); p1 = fmaf(a1.y, wr1.x, p1);
            p1 = fmaf(x1.x, wo0.x, p1);         p1 = fmaf(x1.y, wo1.x, p1);
            float q1 = fmaf(a1.x, wr0.y, bb.y); q1 = fmaf(a1.y, wr1.y, q1);
            q1 = fmaf(x1.x, wo0.y, q1);         q1 = fmaf(x1.y, wo1.y, q1);
            acc.x = fmaf(w1, fmaxf(p1, 0.f), acc.x);
            acc.y = fmaf(w1, fmaxf(q1, 0.f), acc.y);
        }
        if (k < nb) {   // odd tail
            int   s0 = __shfl(sx, k);
            float w0 = __int_as_float(__shfl(wb, k));
            float2 a0 = aggr1[s0];
            float2 x0 = *reinterpret_cast<const float2*>(x + (size_t)s0 * 2);
            float p0 = fmaf(a0.x, wr0.x, bb.x); p0 = fmaf(a0.y, wr1.x, p0);
            p0 = fmaf(x0.x, wo0.x, p0);         p0 = fmaf(x0.y, wo1.x, p0);
            float q0 = fmaf(a0.x, wr0.y, bb.y); q0 = fmaf(a0.y, wr1.y, q0);
            q0 = fmaf(x0.x, wo0.y, q0);         q0 = fmaf(x0.y, wo1.y, q0);
            acc.x = fmaf(w0, fmaxf(p0, 0.f), acc.x);
            acc.y = fmaf(w0, fmaxf(q0, 0.f), acc.y);
        }
    }
    *reinterpret_cast<float2*>(aggr + (size_t)wv * HIDDEN + c0) = acc;

    // fused k_node1: this wave's own h1 row
    {
        float2 a  = aggr1[wv];
        float2 xv = *reinterpret_cast<const float2*>(x + (size_t)wv * 2);
        float p = fmaf(a.x, wr0.x, bb.x); p = fmaf(a.y, wr1.x, p);
        p = fmaf(xv.x, wo0.x, p);         p = fmaf(xv.y, wo1.x, p);
        float q = fmaf(a.x, wr0.y, bb.y); q = fmaf(a.y, wr1.y, q);
        q = fmaf(xv.x, wo0.y, q);         q = fmaf(xv.y, wo1.y, q);
        *reinterpret_cast<float2*>(h + (size_t)wv * HIDDEN + c0) =
            make_float2(fmaxf(p, 0.f), fmaxf(q, 0.f));
    }
}

// ================= layer 2 node update: LDS-tiled fp32 GEMM =================
// h2 = relu([aggr | h] @ [W2rel ; W2root] + b2), written IN PLACE over h.
#define BM2 64
#define XS_STRIDE 68   // 64 + 4 pad: float4 alignment + bank spread

__global__ __launch_bounds__(256)
void k_node2(const float* __restrict__ aggr, float* __restrict__ h,
             const float* __restrict__ Wrel, const float* __restrict__ b,
             const float* __restrict__ Wroot, int N) {
    __shared__ float Xs[BM2 * XS_STRIDE];     // 64 x 64 input tile (+pad)
    __shared__ float Ws[64 * HIDDEN];         // 64 x 128 weight tile

    const int tid = threadIdx.x;
    const int ci  = tid & 15;                 // channel group: cols ci*4, 64+ci*4
    const int ri  = tid >> 4;                 // node group: rows ri*4 .. ri*4+3
    const int nb  = blockIdx.x * BM2;

    float acc[4][8];
    {
        float4 b0 = *reinterpret_cast<const float4*>(b + ci * 4);
        float4 b1 = *reinterpret_cast<const float4*>(b + 64 + ci * 4);
#pragma unroll
        for (int m = 0; m < 4; ++m) {
            acc[m][0] = b0.x; acc[m][1] = b0.y; acc[m][2] = b0.z; acc[m][3] = b0.w;
            acc[m][4] = b1.x; acc[m][5] = b1.y; acc[m][6] = b1.z; acc[m][7] = b1.w;
        }
    }

    for (int t = 0; t < 4; ++t) {
        const float* Xsrc = (t < 2) ? aggr : (const float*)h;
        const float* Wsrc = (t < 2) ? Wrel : Wroot;
        const int kc = (t & 1) * 64;

        __syncthreads();
#pragma unroll
        for (int q = 0; q < 4; ++q) {
            int idx = q * 256 + tid;
            int row = idx >> 4;
            int c4  = (idx & 15) * 4;
            int gr  = nb + row; if (gr >= N) gr = N - 1;
            float4 v = *reinterpret_cast<const float4*>(Xsrc + (size_t)gr * HIDDEN + kc + c4);
            *reinterpret_cast<float4*>(&Xs[row * XS_STRIDE + c4]) = v;
        }
#pragma unroll
        for (int q = 0; q < 8; ++q) {
            int idx = q * 256 + tid;
            int row = idx >> 5;
            int c4  = (idx & 31) * 4;
            float4 v = *reinterpret_cast<const float4*>(Wsrc + (size_t)(kc + row) * HIDDEN + c4);
            *reinterpret_cast<float4*>(&Ws[row * HIDDEN + c4]) = v;
        }
        __syncthreads();

#pragma unroll
        for (int kk = 0; kk < 64; kk += 4) {
            float4 xr[4];
#pragma unroll
            for (int m = 0; m < 4; ++m)
                xr[m] = *reinterpret_cast<const float4*>(&Xs[(ri * 4 + m) * XS_STRIDE + kk]);
#pragma unroll
            for (int j = 0; j < 4; ++j) {
                float4 w0 = *reinterpret_cast<const float4*>(&Ws[(kk + j) * HIDDEN + ci * 4]);
                float4 w1 = *reinterpret_cast<const float4*>(&Ws[(kk + j) * HIDDEN + 64 + ci * 4]);
#pragma unroll
                for (int m = 0; m < 4; ++m) {
                    float xm = (j == 0) ? xr[m].x : (j == 1) ? xr[m].y
                             : (j == 2) ? xr[m].z : xr[m].w;
                    acc[m][0] = fmaf(xm, w0.x, acc[m][0]);
                    acc[m][1] = fmaf(xm, w0.y, acc[m][1]);
                    acc[m][2] = fmaf(xm, w0.z, acc[m][2]);
                    acc[m][3] = fmaf(xm, w0.w, acc[m][3]);
                    acc[m][4] = fmaf(xm, w1.x, acc[m][4]);
                    acc[m][5] = fmaf(xm, w1.y, acc[m][5]);
                    acc[m][6] = fmaf(xm, w1.z, acc[m][6]);
                    acc[m][7] = fmaf(xm, w1.w, acc[m][7]);
                }
            }
        }
    }

#pragma unroll
    for (int m = 0; m < 4; ++m) {
        int node = nb + ri * 4 + m;
        if (node < N) {
            float4 o0, o1;
            o0.x = fmaxf(acc[m][0], 0.f); o0.y = fmaxf(acc[m][1], 0.f);
            o0.z = fmaxf(acc[m][2], 0.f); o0.w = fmaxf(acc[m][3], 0.f);
            o1.x = fmaxf(acc[m][4], 0.f); o1.y = fmaxf(acc[m][5], 0.f);
            o1.z = fmaxf(acc[m][6], 0.f); o1.w = fmaxf(acc[m][7], 0.f);
            float* o = h + (size_t)node * HIDDEN;
            *reinterpret_cast<float4*>(o + ci * 4)      = o0;
            *reinterpret_cast<float4*>(o + 64 + ci * 4) = o1;
        }
    }
}

// ================= layer 3: project to 3ch, then gather =====================
__global__ __launch_bounds__(256)
void k_node3(const float* __restrict__ h2,
             const float* __restrict__ Wrel, const float* __restrict__ b,
             const float* __restrict__ Wroot,
             float* __restrict__ z, float* __restrict__ out, int N) {
    int i = blockIdx.x * 256 + threadIdx.x;
    if (i >= N) return;
    float zr[3] = {0.f, 0.f, 0.f};
    float zo[3] = {b[0], b[1], b[2]};
    const float4* h4 = reinterpret_cast<const float4*>(h2 + (size_t)i * HIDDEN);
    for (int kk = 0; kk < HIDDEN / 4; ++kk) {
        float4 hv = h4[kk];
#pragma unroll
        for (int j = 0; j < 4; ++j) {
            int k = kk * 4 + j;
            float hj = (j == 0) ? hv.x : (j == 1) ? hv.y : (j == 2) ? hv.z : hv.w;
#pragma unroll
            for (int c = 0; c < 3; ++c) {
                zr[c] = fmaf(hj, Wrel [k * 3 + c], zr[c]);
                zo[c] = fmaf(hj, Wroot[k * 3 + c], zo[c]);
            }
        }
    }
    z[(size_t)i * 3 + 0] = zr[0]; z[(size_t)i * 3 + 1] = zr[1]; z[(size_t)i * 3 + 2] = zr[2];
    out[(size_t)i * 3 + 0] = zo[0]; out[(size_t)i * 3 + 1] = zo[1]; out[(size_t)i * 3 + 2] = zo[2];
}

__global__ __launch_bounds__(256)
void k_gather3(const int* __restrict__ offs, const int2* __restrict__ cpack,
               const float* __restrict__ z, float* __restrict__ out,
               int N, int E) {
    int i = blockIdx.x * 256 + threadIdx.x;
    if (i >= N) return;
    int start = offs[i], deg = deg_of(offs, i, N, E);
    float a0 = 0.f, a1 = 0.f, a2 = 0.f;
    for (int j = 0; j < deg; ++j) {
        int2  p = cpack[start + j];
        int   s = p.x;
        float w = __int_as_float(p.y);
        const float* zp = z + (size_t)s * 3;
        a0 = fmaf(w, zp[0], a0);
        a1 = fmaf(w, zp[1], a1);
        a2 = fmaf(w, zp[2], a2);
    }
    out[(size_t)i * 3 + 0] += a0;
    out[(size_t)i * 3 + 1] += a1;
    out[(size_t)i * 3 + 2] += a2;
}

extern "C" void kernel_launch(void* const* d_in, const int* in_sizes, int n_in,
                              void* d_out, int out_size, void* d_ws, size_t ws_size,
                              hipStream_t stream) {
    const float* x      = (const float*)d_in[0];
    const int*   ei     = (const int*)  d_in[1];
    const float* ew     = (const float*)d_in[2];
    const float* W1rel  = (const float*)d_in[4];
    const float* b1     = (const float*)d_in[5];
    const float* W1root = (const float*)d_in[6];
    const float* W2rel  = (const float*)d_in[7];
    const float* b2     = (const float*)d_in[8];
    const float* W2root = (const float*)d_in[9];
    const float* W3rel  = (const float*)d_in[10];
    const float* b3     = (const float*)d_in[11];
    const float* W3root = (const float*)d_in[12];
    float* out = (float*)d_out;

    const int N = in_sizes[0] / 2;
    const int E = in_sizes[2];
    const int* src = ei;
    const int* dst = ei + E;

    // -------- workspace layout (116.4 MB — parity with original session) ----
    // h     : N*128 f32   (h1, overwritten in place by h2; front E ints alias
    //         rank during CSR build — rank dead before gatherfused writes h)
    // aggr  : N*128 f32   (layer-2 aggregation; front N*3 reused for z)
    // offs  : N int | bsum : SCAN_B int
    // cpack : E int2      (front N ints alias cnt — cnt dead before k_fill)
    // aggr1 : N float2    (layer-1 aggregation, L2-resident gather target)
    float* h    = (float*)d_ws;
    float* aggr = h + (size_t)N * HIDDEN;
    int*   offs = (int*)(aggr + (size_t)N * HIDDEN);
    int*   bsum = offs + N;
    size_t cpo  = (size_t)(bsum + SCAN_B - (int*)d_ws);
    cpo = (cpo + 1) & ~(size_t)1;          // 8B alignment
    int2*   cpack = (int2*)((int*)d_ws + cpo);
    float2* aggr1 = (float2*)(cpack + E);
    int* cnt  = (int*)cpack;               // alias: dead before k_fill writes cpack
    int* rank = (int*)h;                   // alias: dead before gatherfused writes h

    const int nbScan = (N + SCAN_B - 1) / SCAN_B;

    // -------- CSR build --------
    hipMemsetAsync(cnt, 0, (size_t)N * sizeof(int), stream);
    k_hist <<<(E + 255) / 256, 256, 0, stream>>>(dst, cnt, rank, E);
    k_scan1<<<nbScan, SCAN_B, 0, stream>>>(cnt, offs, bsum, N);
    k_scan2<<<1, SCAN_B, 0, stream>>>(bsum, nbScan);
    k_scan3<<<nbScan, SCAN_B, 0, stream>>>(offs, bsum, N);
    k_fill <<<(E + 255) / 256, 256, 0, stream>>>(src, dst, ew, offs, rank, cpack, E);

    // -------- layer 1 aggregation (2ch) --------
    k_gather2<<<(N + 255) / 256, 256, 0, stream>>>(offs, cpack, x, aggr1, N, E);

    // -------- fused layer-2 aggregation + layer-1 node update --------
    {
        long long threads = (long long)N * 64;
        k_gatherfused<<<(int)((threads + 255) / 256), 256, 0, stream>>>(
            offs, cpack, aggr1, x, W1rel, b1, W1root, h, aggr, N, E);
    }

    // -------- layer 2 node update --------
    k_node2<<<(N + BM2 - 1) / BM2, 256, 0, stream>>>(aggr, h, W2rel, b2, W2root, N);

    // -------- layer 3 --------
    float* z = aggr;   // aggr dead after node2; reuse front N*3 for z
    k_node3  <<<(N + 255) / 256, 256, 0, stream>>>(h, W3rel, b3, W3root, z, out, N);
    k_gather3<<<(N + 255) / 256, 256, 0, stream>>>(offs, cpack, z, out, N, E);
}